// Round 1
// baseline (56.894 us; speedup 1.0000x reference)
//
#include <hip/hip_runtime.h>

// NIoULoss_pixel: B=8, N=8, H=W=512.
// Five reductions per (b,n) over HW, fused in one memory-bound pass.

constexpr int Bc  = 8;
constexpr int Nc  = 8;
constexpr int HWc = 512 * 512;
constexpr float EPSc = 1e-6f;

__device__ __forceinline__ float wave_reduce(float v) {
#pragma unroll
    for (int off = 32; off; off >>= 1) v += __shfl_xor(v, off, 64);
    return v;
}

// 256 blocks per image, 256 threads/block, 1 quad (4 pixels) per thread.
__global__ __launch_bounds__(256) void niou_partial(
    const float* __restrict__ pd, const float* __restrict__ gt,
    const int* __restrict__ pmask, const int* __restrict__ gmask,
    float* __restrict__ ws /* [B][N][5] */)
{
    const int b    = blockIdx.x >> 8;     // image
    const int blk  = blockIdx.x & 255;    // chunk within image
    const int quad = blk * 256 + threadIdx.x;   // 0..65535
    const size_t p = (size_t)quad * 4;          // pixel offset in HW
    constexpr int HW4 = HWc / 4;

    const float4* pd4 = reinterpret_cast<const float4*>(pd + (size_t)b * 4 * HWc + p);
    const float4* gt4 = reinterpret_cast<const float4*>(gt + (size_t)b * 4 * HWc + p);

    const float4 p0 = pd4[0], p1 = pd4[HW4], p2 = pd4[2 * HW4], p3 = pd4[3 * HW4];
    const float4 g0 = gt4[0], g1 = gt4[HW4], g2 = gt4[2 * HW4], g3 = gt4[3 * HW4];

    float dn[4], po[4], go[4];
    {
        float dx, dy, dz;
        dx = p0.x - g0.x; dy = p1.x - g1.x; dz = p2.x - g2.x;
        dn[0] = sqrtf(dx*dx + dy*dy + dz*dz); po[0] = rintf(p3.x); go[0] = rintf(g3.x);
        dx = p0.y - g0.y; dy = p1.y - g1.y; dz = p2.y - g2.y;
        dn[1] = sqrtf(dx*dx + dy*dy + dz*dz); po[1] = rintf(p3.y); go[1] = rintf(g3.y);
        dx = p0.z - g0.z; dy = p1.z - g1.z; dz = p2.z - g2.z;
        dn[2] = sqrtf(dx*dx + dy*dy + dz*dz); po[2] = rintf(p3.z); go[2] = rintf(g3.z);
        dx = p0.w - g0.w; dy = p1.w - g1.w; dz = p2.w - g2.w;
        dn[3] = sqrtf(dx*dx + dy*dy + dz*dz); po[3] = rintf(p3.w); go[3] = rintf(g3.w);
    }

    // acc[n][q]: q = {sim_sum, count, inter, gt_sum, pd_xor_sum}
    float acc[Nc][5];
#pragma unroll
    for (int n = 0; n < Nc; ++n)
#pragma unroll
        for (int q = 0; q < 5; ++q) acc[n][q] = 0.f;

#pragma unroll
    for (int n = 0; n < Nc; ++n) {
        const size_t moff = ((size_t)(b * Nc + n)) * HWc + p;
        const int4 pmv = *reinterpret_cast<const int4*>(pmask + moff);
        const int4 gmv = *reinterpret_cast<const int4*>(gmask + moff);
        const int pmx[4] = {pmv.x, pmv.y, pmv.z, pmv.w};
        const int gmx[4] = {gmv.x, gmv.y, gmv.z, gmv.w};
#pragma unroll
        for (int j = 0; j < 4; ++j) {
            const bool P = pmx[j] != 0;
            const bool G = gmx[j] != 0;
            acc[n][0] += P ? dn[j] : 0.f;
            acc[n][1] += P ? 1.f  : 0.f;
            acc[n][2] += (P && G)  ? po[j] : 0.f;
            acc[n][3] += G ? go[j] : 0.f;
            acc[n][4] += (P && !G) ? po[j] : 0.f;
        }
    }

    __shared__ float red[4][40];
    const int lane = threadIdx.x & 63;
    const int wv   = threadIdx.x >> 6;
#pragma unroll
    for (int n = 0; n < Nc; ++n)
#pragma unroll
        for (int q = 0; q < 5; ++q) {
            const float v = wave_reduce(acc[n][q]);
            if (lane == 0) red[wv][n * 5 + q] = v;
        }
    __syncthreads();

    const int t = threadIdx.x;
    if (t < Nc * 5) {
        const float v = red[0][t] + red[1][t] + red[2][t] + red[3][t];
        atomicAdd(&ws[b * (Nc * 5) + t], v);
    }
}

__global__ __launch_bounds__(64) void niou_final(
    const float* __restrict__ ws, float* __restrict__ out)
{
    const int t = threadIdx.x;   // 0..63 == b*8+n
    const float* w = ws + t * 5;
    const float sim   = w[0];
    const float cnt   = w[1];
    const float inter = w[2];
    const float gts   = w[3];
    const float xo    = w[4];
    const float punish = sim / (cnt + EPSc);
    const float iou    = inter / (gts + xo + EPSc);
    float term = 1.0f - iou + punish;
    term = wave_reduce(term);
    if (t == 0) out[0] = term * (1.0f / 64.0f);
}

extern "C" void kernel_launch(void* const* d_in, const int* in_sizes, int n_in,
                              void* d_out, int out_size, void* d_ws, size_t ws_size,
                              hipStream_t stream) {
    const float* pd_rgbo = (const float*)d_in[0];
    const float* gt_rgbo = (const float*)d_in[1];
    const int*   pd_mask = (const int*)d_in[2];
    const int*   gt_mask = (const int*)d_in[3];
    float* out = (float*)d_out;
    float* ws  = (float*)d_ws;

    hipMemsetAsync(ws, 0, Bc * Nc * 5 * sizeof(float), stream);
    niou_partial<<<Bc * 256, 256, 0, stream>>>(pd_rgbo, gt_rgbo, pd_mask, gt_mask, ws);
    niou_final<<<1, 64, 0, stream>>>(ws, out);
}

// Round 2
// 56.248 us; speedup vs baseline: 1.0115x; 1.0115x over previous
//
#include <hip/hip_runtime.h>

// NIoULoss_pixel: B=8, N=8, H=W=512. One-pass fused reduction.
// R2: hoist all 24 global loads into flight (explicit reg arrays) to fix the
// latency-bound serialization seen in R1 (VGPR=52 proved loads weren't hoisted);
// pad atomic counters to one cacheline each.

constexpr int Bc  = 8;
constexpr int Nc  = 8;
constexpr int HWc = 512 * 512;
constexpr int PAD = 16;               // floats per counter slot (64 B line)
constexpr float EPSc = 1e-6f;

__device__ __forceinline__ float wave_reduce(float v) {
#pragma unroll
    for (int off = 32; off; off >>= 1) v += __shfl_xor(v, off, 64);
    return v;
}

// 256 blocks per image, 256 threads/block, 1 quad (4 pixels) per thread.
__global__ __launch_bounds__(256) void niou_partial(
    const float* __restrict__ pd, const float* __restrict__ gt,
    const int* __restrict__ pmask, const int* __restrict__ gmask,
    float* __restrict__ ws /* [B][40][PAD] */)
{
    const int b    = blockIdx.x >> 8;
    const int blk  = blockIdx.x & 255;
    const int quad = blk * 256 + threadIdx.x;
    const size_t p = (size_t)quad * 4;
    constexpr int HW4 = HWc / 4;

    const float4* pd4 = reinterpret_cast<const float4*>(pd + (size_t)b * 4 * HWc + p);
    const float4* gt4 = reinterpret_cast<const float4*>(gt + (size_t)b * 4 * HWc + p);
    const int4*   pm4 = reinterpret_cast<const int4*>(pmask + (size_t)b * Nc * HWc + p);
    const int4*   gm4 = reinterpret_cast<const int4*>(gmask + (size_t)b * Nc * HWc + p);

    // ---- issue ALL loads before any use ----
    float4 pv[4], gv[4];
#pragma unroll
    for (int c = 0; c < 4; ++c) pv[c] = pd4[c * HW4];
#pragma unroll
    for (int c = 0; c < 4; ++c) gv[c] = gt4[c * HW4];

    int4 pmv[Nc], gmv[Nc];
#pragma unroll
    for (int n = 0; n < Nc; ++n) { pmv[n] = pm4[n * HW4]; gmv[n] = gm4[n * HW4]; }

    // ---- per-pixel quantities (waits only on the 8 rgbo loads) ----
    float dn[4], po[4], go[4];
    {
        float dx, dy, dz;
        dx = pv[0].x - gv[0].x; dy = pv[1].x - gv[1].x; dz = pv[2].x - gv[2].x;
        dn[0] = sqrtf(dx*dx + dy*dy + dz*dz); po[0] = rintf(pv[3].x); go[0] = rintf(gv[3].x);
        dx = pv[0].y - gv[0].y; dy = pv[1].y - gv[1].y; dz = pv[2].y - gv[2].y;
        dn[1] = sqrtf(dx*dx + dy*dy + dz*dz); po[1] = rintf(pv[3].y); go[1] = rintf(gv[3].y);
        dx = pv[0].z - gv[0].z; dy = pv[1].z - gv[1].z; dz = pv[2].z - gv[2].z;
        dn[2] = sqrtf(dx*dx + dy*dy + dz*dz); po[2] = rintf(pv[3].z); go[2] = rintf(gv[3].z);
        dx = pv[0].w - gv[0].w; dy = pv[1].w - gv[1].w; dz = pv[2].w - gv[2].w;
        dn[3] = sqrtf(dx*dx + dy*dy + dz*dz); po[3] = rintf(pv[3].w); go[3] = rintf(gv[3].w);
    }

    // acc[n][q]: q = {sim_sum, count, inter, gt_sum, pd_xor_sum}
    float acc[Nc][5];
#pragma unroll
    for (int n = 0; n < Nc; ++n)
#pragma unroll
        for (int q = 0; q < 5; ++q) acc[n][q] = 0.f;

#pragma unroll
    for (int n = 0; n < Nc; ++n) {
        const int pmx[4] = {pmv[n].x, pmv[n].y, pmv[n].z, pmv[n].w};
        const int gmx[4] = {gmv[n].x, gmv[n].y, gmv[n].z, gmv[n].w};
#pragma unroll
        for (int j = 0; j < 4; ++j) {
            const bool P = pmx[j] != 0;
            const bool G = gmx[j] != 0;
            acc[n][0] += P ? dn[j] : 0.f;
            acc[n][1] += P ? 1.f  : 0.f;
            acc[n][2] += (P && G)  ? po[j] : 0.f;
            acc[n][3] += G ? go[j] : 0.f;
            acc[n][4] += (P && !G) ? po[j] : 0.f;
        }
    }

    __shared__ float red[4][40];
    const int lane = threadIdx.x & 63;
    const int wv   = threadIdx.x >> 6;
#pragma unroll
    for (int n = 0; n < Nc; ++n)
#pragma unroll
        for (int q = 0; q < 5; ++q) {
            const float v = wave_reduce(acc[n][q]);
            if (lane == 0) red[wv][n * 5 + q] = v;
        }
    __syncthreads();

    const int t = threadIdx.x;
    if (t < Nc * 5) {
        const float v = red[0][t] + red[1][t] + red[2][t] + red[3][t];
        atomicAdd(&ws[(b * 40 + t) * PAD], v);   // one cacheline per counter
    }
}

__global__ __launch_bounds__(64) void niou_final(
    const float* __restrict__ ws, float* __restrict__ out)
{
    const int t = threadIdx.x;   // 0..63 == b*8+n
    const float* w = ws + (size_t)t * 5 * PAD;
    const float sim   = w[0 * PAD];
    const float cnt   = w[1 * PAD];
    const float inter = w[2 * PAD];
    const float gts   = w[3 * PAD];
    const float xo    = w[4 * PAD];
    const float punish = sim / (cnt + EPSc);
    const float iou    = inter / (gts + xo + EPSc);
    float term = 1.0f - iou + punish;
    term = wave_reduce(term);
    if (t == 0) out[0] = term * (1.0f / 64.0f);
}

extern "C" void kernel_launch(void* const* d_in, const int* in_sizes, int n_in,
                              void* d_out, int out_size, void* d_ws, size_t ws_size,
                              hipStream_t stream) {
    const float* pd_rgbo = (const float*)d_in[0];
    const float* gt_rgbo = (const float*)d_in[1];
    const int*   pd_mask = (const int*)d_in[2];
    const int*   gt_mask = (const int*)d_in[3];
    float* out = (float*)d_out;
    float* ws  = (float*)d_ws;

    hipMemsetAsync(ws, 0, Bc * 40 * PAD * sizeof(float), stream);
    niou_partial<<<Bc * 256, 256, 0, stream>>>(pd_rgbo, gt_rgbo, pd_mask, gt_mask, ws);
    niou_final<<<1, 64, 0, stream>>>(ws, out);
}

// Round 3
// 54.742 us; speedup vs baseline: 1.0393x; 1.0275x over previous
//
#include <hip/hip_runtime.h>

// NIoULoss_pixel: B=8, N=8, H=W=512. One-pass fused reduction.
// R3: __launch_bounds__(256,3) — R2 showed the default 8-waves/SIMD target
// capped VGPR at 64 and re-serialized the hoisted loads (VGPR stayed 56).
// With a ~170-VGPR budget all 24 16B loads/thread can be in flight.

constexpr int Bc  = 8;
constexpr int Nc  = 8;
constexpr int HWc = 512 * 512;
constexpr int PAD = 16;               // floats per counter slot (64 B line)
constexpr float EPSc = 1e-6f;

__device__ __forceinline__ float wave_reduce(float v) {
#pragma unroll
    for (int off = 32; off; off >>= 1) v += __shfl_xor(v, off, 64);
    return v;
}

// 256 blocks per image, 256 threads/block, 1 quad (4 pixels) per thread.
__global__ __launch_bounds__(256, 3) void niou_partial(
    const float* __restrict__ pd, const float* __restrict__ gt,
    const int* __restrict__ pmask, const int* __restrict__ gmask,
    float* __restrict__ ws /* [B][40][PAD] */)
{
    const int b    = blockIdx.x >> 8;
    const int blk  = blockIdx.x & 255;
    const int quad = blk * 256 + threadIdx.x;
    const size_t p = (size_t)quad * 4;
    constexpr int HW4 = HWc / 4;

    const float4* pd4 = reinterpret_cast<const float4*>(pd + (size_t)b * 4 * HWc + p);
    const float4* gt4 = reinterpret_cast<const float4*>(gt + (size_t)b * 4 * HWc + p);
    const int4*   pm4 = reinterpret_cast<const int4*>(pmask + (size_t)b * Nc * HWc + p);
    const int4*   gm4 = reinterpret_cast<const int4*>(gmask + (size_t)b * Nc * HWc + p);

    // ---- issue ALL loads before any use ----
    float4 pv[4], gv[4];
#pragma unroll
    for (int c = 0; c < 4; ++c) pv[c] = pd4[c * HW4];
#pragma unroll
    for (int c = 0; c < 4; ++c) gv[c] = gt4[c * HW4];

    int4 pmv[Nc], gmv[Nc];
#pragma unroll
    for (int n = 0; n < Nc; ++n) { pmv[n] = pm4[n * HW4]; gmv[n] = gm4[n * HW4]; }

    // ---- per-pixel quantities (waits only on the 8 rgbo loads) ----
    float dn[4], po[4], go[4];
    {
        float dx, dy, dz;
        dx = pv[0].x - gv[0].x; dy = pv[1].x - gv[1].x; dz = pv[2].x - gv[2].x;
        dn[0] = sqrtf(dx*dx + dy*dy + dz*dz); po[0] = rintf(pv[3].x); go[0] = rintf(gv[3].x);
        dx = pv[0].y - gv[0].y; dy = pv[1].y - gv[1].y; dz = pv[2].y - gv[2].y;
        dn[1] = sqrtf(dx*dx + dy*dy + dz*dz); po[1] = rintf(pv[3].y); go[1] = rintf(gv[3].y);
        dx = pv[0].z - gv[0].z; dy = pv[1].z - gv[1].z; dz = pv[2].z - gv[2].z;
        dn[2] = sqrtf(dx*dx + dy*dy + dz*dz); po[2] = rintf(pv[3].z); go[2] = rintf(gv[3].z);
        dx = pv[0].w - gv[0].w; dy = pv[1].w - gv[1].w; dz = pv[2].w - gv[2].w;
        dn[3] = sqrtf(dx*dx + dy*dy + dz*dz); po[3] = rintf(pv[3].w); go[3] = rintf(gv[3].w);
    }

    // acc[n][q]: q = {sim_sum, count, inter, gt_sum, pd_xor_sum}
    float acc[Nc][5];
#pragma unroll
    for (int n = 0; n < Nc; ++n)
#pragma unroll
        for (int q = 0; q < 5; ++q) acc[n][q] = 0.f;

#pragma unroll
    for (int n = 0; n < Nc; ++n) {
        const int pmx[4] = {pmv[n].x, pmv[n].y, pmv[n].z, pmv[n].w};
        const int gmx[4] = {gmv[n].x, gmv[n].y, gmv[n].z, gmv[n].w};
#pragma unroll
        for (int j = 0; j < 4; ++j) {
            const bool P = pmx[j] != 0;
            const bool G = gmx[j] != 0;
            acc[n][0] += P ? dn[j] : 0.f;
            acc[n][1] += P ? 1.f  : 0.f;
            acc[n][2] += (P && G)  ? po[j] : 0.f;
            acc[n][3] += G ? go[j] : 0.f;
            acc[n][4] += (P && !G) ? po[j] : 0.f;
        }
    }

    __shared__ float red[4][40];
    const int lane = threadIdx.x & 63;
    const int wv   = threadIdx.x >> 6;
#pragma unroll
    for (int n = 0; n < Nc; ++n)
#pragma unroll
        for (int q = 0; q < 5; ++q) {
            const float v = wave_reduce(acc[n][q]);
            if (lane == 0) red[wv][n * 5 + q] = v;
        }
    __syncthreads();

    const int t = threadIdx.x;
    if (t < Nc * 5) {
        const float v = red[0][t] + red[1][t] + red[2][t] + red[3][t];
        atomicAdd(&ws[(b * 40 + t) * PAD], v);   // one cacheline per counter
    }
}

__global__ __launch_bounds__(64) void niou_final(
    const float* __restrict__ ws, float* __restrict__ out)
{
    const int t = threadIdx.x;   // 0..63 == b*8+n
    const float* w = ws + (size_t)t * 5 * PAD;
    const float sim   = w[0 * PAD];
    const float cnt   = w[1 * PAD];
    const float inter = w[2 * PAD];
    const float gts   = w[3 * PAD];
    const float xo    = w[4 * PAD];
    const float punish = sim / (cnt + EPSc);
    const float iou    = inter / (gts + xo + EPSc);
    float term = 1.0f - iou + punish;
    term = wave_reduce(term);
    if (t == 0) out[0] = term * (1.0f / 64.0f);
}

extern "C" void kernel_launch(void* const* d_in, const int* in_sizes, int n_in,
                              void* d_out, int out_size, void* d_ws, size_t ws_size,
                              hipStream_t stream) {
    const float* pd_rgbo = (const float*)d_in[0];
    const float* gt_rgbo = (const float*)d_in[1];
    const int*   pd_mask = (const int*)d_in[2];
    const int*   gt_mask = (const int*)d_in[3];
    float* out = (float*)d_out;
    float* ws  = (float*)d_ws;

    hipMemsetAsync(ws, 0, Bc * 40 * PAD * sizeof(float), stream);
    niou_partial<<<Bc * 256, 256, 0, stream>>>(pd_rgbo, gt_rgbo, pd_mask, gt_mask, ws);
    niou_final<<<1, 64, 0, stream>>>(ws, out);
}

// Round 4
// 44.665 us; speedup vs baseline: 1.2738x; 1.2256x over previous
//
#include <hip/hip_runtime.h>

// NIoULoss_pixel: B=8, N=8, H=W=512. One-pass fused reduction.
// R4: force load batching with sched_barrier(0) (R2/R3 proved the scheduler
// sinks loads to uses otherwise — VGPR stayed ~50); R=2 quads/thread to
// amortize the shuffle epilogue; count via __ballot popcount (scalar pipe,
// kills 8 of 40 butterfly reductions).

constexpr int Bc  = 8;
constexpr int Nc  = 8;
constexpr int HWc = 512 * 512;
constexpr int PAD = 16;               // floats per counter slot (64 B line)
constexpr int R   = 2;                // quads per thread
constexpr int QPB = 256 * R;          // quads per block
constexpr float EPSc = 1e-6f;

__device__ __forceinline__ float wave_reduce(float v) {
#pragma unroll
    for (int off = 32; off; off >>= 1) v += __shfl_xor(v, off, 64);
    return v;
}

// 128 blocks per image, 256 threads/block, R quads per thread.
__global__ __launch_bounds__(256, 2) void niou_partial(
    const float* __restrict__ pd, const float* __restrict__ gt,
    const int* __restrict__ pmask, const int* __restrict__ gmask,
    float* __restrict__ ws /* [B][40][PAD] */)
{
    const int b   = blockIdx.x >> 7;
    const int blk = blockIdx.x & 127;
    constexpr int HW4 = HWc / 4;

    // acc[n]: {sim_sum, inter, gt_sum, pd_xor_sum}; count via ballot (wave-uniform)
    float acc[Nc][4];
    int   wcnt[Nc];
#pragma unroll
    for (int n = 0; n < Nc; ++n) {
        wcnt[n] = 0;
#pragma unroll
        for (int q = 0; q < 4; ++q) acc[n][q] = 0.f;
    }

#pragma unroll
    for (int r = 0; r < R; ++r) {
        const int quad = blk * QPB + r * 256 + threadIdx.x;
        const size_t p = (size_t)quad * 4;

        const float4* pd4 = reinterpret_cast<const float4*>(pd + (size_t)b * 4 * HWc + p);
        const float4* gt4 = reinterpret_cast<const float4*>(gt + (size_t)b * 4 * HWc + p);
        const int4*   pm4 = reinterpret_cast<const int4*>(pmask + (size_t)b * Nc * HWc + p);
        const int4*   gm4 = reinterpret_cast<const int4*>(gmask + (size_t)b * Nc * HWc + p);

        // ---- issue ALL 24 loads, then fence the scheduler ----
        float4 pv[4], gv[4];
        int4 pmv[Nc], gmv[Nc];
#pragma unroll
        for (int c = 0; c < 4; ++c) pv[c] = pd4[c * HW4];
#pragma unroll
        for (int c = 0; c < 4; ++c) gv[c] = gt4[c * HW4];
#pragma unroll
        for (int n = 0; n < Nc; ++n) { pmv[n] = pm4[n * HW4]; gmv[n] = gm4[n * HW4]; }
        __builtin_amdgcn_sched_barrier(0);   // nothing crosses: loads stay batched

        // ---- per-pixel quantities ----
        float dn[4], po[4], go[4];
        {
            float dx, dy, dz;
            dx = pv[0].x - gv[0].x; dy = pv[1].x - gv[1].x; dz = pv[2].x - gv[2].x;
            dn[0] = sqrtf(dx*dx + dy*dy + dz*dz); po[0] = rintf(pv[3].x); go[0] = rintf(gv[3].x);
            dx = pv[0].y - gv[0].y; dy = pv[1].y - gv[1].y; dz = pv[2].y - gv[2].y;
            dn[1] = sqrtf(dx*dx + dy*dy + dz*dz); po[1] = rintf(pv[3].y); go[1] = rintf(gv[3].y);
            dx = pv[0].z - gv[0].z; dy = pv[1].z - gv[1].z; dz = pv[2].z - gv[2].z;
            dn[2] = sqrtf(dx*dx + dy*dy + dz*dz); po[2] = rintf(pv[3].z); go[2] = rintf(gv[3].z);
            dx = pv[0].w - gv[0].w; dy = pv[1].w - gv[1].w; dz = pv[2].w - gv[2].w;
            dn[3] = sqrtf(dx*dx + dy*dy + dz*dz); po[3] = rintf(pv[3].w); go[3] = rintf(gv[3].w);
        }

#pragma unroll
        for (int n = 0; n < Nc; ++n) {
            const int pmx[4] = {pmv[n].x, pmv[n].y, pmv[n].z, pmv[n].w};
            const int gmx[4] = {gmv[n].x, gmv[n].y, gmv[n].z, gmv[n].w};
#pragma unroll
            for (int j = 0; j < 4; ++j) {
                const bool P = pmx[j] != 0;
                const bool G = gmx[j] != 0;
                wcnt[n] += __popcll(__ballot(P));          // scalar pipe, wave-uniform
                acc[n][0] += P ? dn[j] : 0.f;
                acc[n][1] += (P && G)  ? po[j] : 0.f;
                acc[n][2] += G ? go[j] : 0.f;
                acc[n][3] += (P && !G) ? po[j] : 0.f;
            }
        }
    }

    // ---- block reduction: 32 butterflies + wave-uniform counts ----
    __shared__ float red[4][40];
    const int lane = threadIdx.x & 63;
    const int wv   = threadIdx.x >> 6;
#pragma unroll
    for (int n = 0; n < Nc; ++n) {
        const float s0 = wave_reduce(acc[n][0]);
        const float s1 = wave_reduce(acc[n][1]);
        const float s2 = wave_reduce(acc[n][2]);
        const float s3 = wave_reduce(acc[n][3]);
        if (lane == 0) {
            red[wv][n * 5 + 0] = s0;
            red[wv][n * 5 + 1] = (float)wcnt[n];
            red[wv][n * 5 + 2] = s1;
            red[wv][n * 5 + 3] = s2;
            red[wv][n * 5 + 4] = s3;
        }
    }
    __syncthreads();

    const int t = threadIdx.x;
    if (t < Nc * 5) {
        const float v = red[0][t] + red[1][t] + red[2][t] + red[3][t];
        atomicAdd(&ws[(b * 40 + t) * PAD], v);   // one cacheline per counter
    }
}

__global__ __launch_bounds__(64) void niou_final(
    const float* __restrict__ ws, float* __restrict__ out)
{
    const int t = threadIdx.x;   // 0..63 == b*8+n
    const float* w = ws + (size_t)t * 5 * PAD;
    const float sim   = w[0 * PAD];
    const float cnt   = w[1 * PAD];
    const float inter = w[2 * PAD];
    const float gts   = w[3 * PAD];
    const float xo    = w[4 * PAD];
    const float punish = sim / (cnt + EPSc);
    const float iou    = inter / (gts + xo + EPSc);
    float term = 1.0f - iou + punish;
    term = wave_reduce(term);
    if (t == 0) out[0] = term * (1.0f / 64.0f);
}

extern "C" void kernel_launch(void* const* d_in, const int* in_sizes, int n_in,
                              void* d_out, int out_size, void* d_ws, size_t ws_size,
                              hipStream_t stream) {
    const float* pd_rgbo = (const float*)d_in[0];
    const float* gt_rgbo = (const float*)d_in[1];
    const int*   pd_mask = (const int*)d_in[2];
    const int*   gt_mask = (const int*)d_in[3];
    float* out = (float*)d_out;
    float* ws  = (float*)d_ws;

    hipMemsetAsync(ws, 0, Bc * 40 * PAD * sizeof(float), stream);
    niou_partial<<<Bc * 128, 256, 0, stream>>>(pd_rgbo, gt_rgbo, pd_mask, gt_mask, ws);
    niou_final<<<1, 64, 0, stream>>>(ws, out);
}

// Round 5
// 43.506 us; speedup vs baseline: 1.3077x; 1.0266x over previous
//
#include <hip/hip_runtime.h>

// NIoULoss_pixel: B=8, N=8, H=W=512. One-pass fused reduction.
// R5: single latency stall per thread — ALL 48 loads (2 quads × (8 rgbo + 16
// mask)) issued before any use, fenced with sched_barrier(0); rgbo oldest so
// dn-compute waits at vmcnt(32) with every mask load still in flight.
// Epilogue: LDS-transpose reduction (one write+one read+one shuffle per
// quantity) replacing 32 full 6-level butterflies.

constexpr int Bc  = 8;
constexpr int Nc  = 8;
constexpr int HWc = 512 * 512;
constexpr int PAD = 16;               // floats per counter slot (64 B line)
constexpr int R   = 2;                // quads per thread
constexpr float EPSc = 1e-6f;

// 128 blocks per image, 256 threads/block, R quads per thread.
__global__ __launch_bounds__(256, 2) void niou_partial(
    const float* __restrict__ pd, const float* __restrict__ gt,
    const int* __restrict__ pmask, const int* __restrict__ gmask,
    float* __restrict__ ws /* [B][40][PAD] */)
{
    const int b    = blockIdx.x >> 7;
    const int blk  = blockIdx.x & 127;
    const int tid  = threadIdx.x;
    constexpr int HW4 = HWc / 4;
    const int quad0 = blk * (256 * R) + tid;

    // ---- issue ALL rgbo loads (oldest), then ALL mask loads, then fence ----
    float4 pv[R][4], gv[R][4];
    int4   pmv[R][Nc], gmv[R][Nc];
#pragma unroll
    for (int r = 0; r < R; ++r) {
        const size_t p = (size_t)(quad0 + r * 256) * 4;
        const float4* pd4 = reinterpret_cast<const float4*>(pd + (size_t)b * 4 * HWc + p);
        const float4* gt4 = reinterpret_cast<const float4*>(gt + (size_t)b * 4 * HWc + p);
#pragma unroll
        for (int c = 0; c < 4; ++c) pv[r][c] = pd4[c * HW4];
#pragma unroll
        for (int c = 0; c < 4; ++c) gv[r][c] = gt4[c * HW4];
    }
    __builtin_amdgcn_sched_barrier(0);   // rgbo batch stays oldest
#pragma unroll
    for (int r = 0; r < R; ++r) {
        const size_t p = (size_t)(quad0 + r * 256) * 4;
        const int4* pm4 = reinterpret_cast<const int4*>(pmask + (size_t)b * Nc * HWc + p);
        const int4* gm4 = reinterpret_cast<const int4*>(gmask + (size_t)b * Nc * HWc + p);
#pragma unroll
        for (int n = 0; n < Nc; ++n) { pmv[r][n] = pm4[n * HW4]; gmv[r][n] = gm4[n * HW4]; }
    }
    __builtin_amdgcn_sched_barrier(0);   // all 48 loads in flight; nothing crosses

    // ---- per-pixel quantities (waits only on the 16 rgbo loads) ----
    float dn[R][4], po[R][4], go[R][4];
#pragma unroll
    for (int r = 0; r < R; ++r) {
        float dx, dy, dz;
        dx = pv[r][0].x - gv[r][0].x; dy = pv[r][1].x - gv[r][1].x; dz = pv[r][2].x - gv[r][2].x;
        dn[r][0] = sqrtf(dx*dx + dy*dy + dz*dz); po[r][0] = rintf(pv[r][3].x); go[r][0] = rintf(gv[r][3].x);
        dx = pv[r][0].y - gv[r][0].y; dy = pv[r][1].y - gv[r][1].y; dz = pv[r][2].y - gv[r][2].y;
        dn[r][1] = sqrtf(dx*dx + dy*dy + dz*dz); po[r][1] = rintf(pv[r][3].y); go[r][1] = rintf(gv[r][3].y);
        dx = pv[r][0].z - gv[r][0].z; dy = pv[r][1].z - gv[r][1].z; dz = pv[r][2].z - gv[r][2].z;
        dn[r][2] = sqrtf(dx*dx + dy*dy + dz*dz); po[r][2] = rintf(pv[r][3].z); go[r][2] = rintf(gv[r][3].z);
        dx = pv[r][0].w - gv[r][0].w; dy = pv[r][1].w - gv[r][1].w; dz = pv[r][2].w - gv[r][2].w;
        dn[r][3] = sqrtf(dx*dx + dy*dy + dz*dz); po[r][3] = rintf(pv[r][3].w); go[r][3] = rintf(gv[r][3].w);
    }

    // acc[n]: {sim_sum, inter, gt_sum, pd_xor_sum}; count via ballot
    float acc[Nc][4];
    int   wcnt[Nc];
#pragma unroll
    for (int n = 0; n < Nc; ++n) {
        wcnt[n] = 0;
#pragma unroll
        for (int q = 0; q < 4; ++q) acc[n][q] = 0.f;
    }

#pragma unroll
    for (int r = 0; r < R; ++r)
#pragma unroll
        for (int n = 0; n < Nc; ++n) {
            const int pmx[4] = {pmv[r][n].x, pmv[r][n].y, pmv[r][n].z, pmv[r][n].w};
            const int gmx[4] = {gmv[r][n].x, gmv[r][n].y, gmv[r][n].z, gmv[r][n].w};
#pragma unroll
            for (int j = 0; j < 4; ++j) {
                const bool P = pmx[j] != 0;
                const bool G = gmx[j] != 0;
                wcnt[n] += __popcll(__ballot(P));
                acc[n][0] += P ? dn[r][j] : 0.f;
                acc[n][1] += (P && G)  ? po[r][j] : 0.f;
                acc[n][2] += G ? go[r][j] : 0.f;
                acc[n][3] += (P && !G) ? po[r][j] : 0.f;
            }
        }

    // ---- LDS-transpose block reduction ----
    __shared__ float tr[256][33];    // stride 33: conflict-free both phases
    __shared__ float part[4][32];    // per-wave partials per quantity
    __shared__ float cpart[4][Nc];   // per-wave ballot counts

    const int wv = tid >> 6;
#pragma unroll
    for (int qi = 0; qi < 32; ++qi) tr[tid][qi] = acc[qi >> 2][qi & 3];
    if ((tid & 63) == 0) {
#pragma unroll
        for (int n = 0; n < Nc; ++n) cpart[wv][n] = (float)wcnt[n];
    }
    __syncthreads();

    {
        const int q    = tid & 31;   // quantity
        const int half = tid >> 5;   // chunk of 32 rows
        float s = 0.f;
#pragma unroll
        for (int k = 0; k < 32; ++k) s += tr[half * 32 + k][q];
        s += __shfl_xor(s, 32, 64);          // combine the two halves in this wave
        if ((tid & 32) == 0) part[tid >> 6][q] = s;
    }
    __syncthreads();

    if (tid < 32) {
        const float v = part[0][tid] + part[1][tid] + part[2][tid] + part[3][tid];
        const int n = tid >> 2, qq = tid & 3;
        const int slot = n * 5 + (qq == 0 ? 0 : qq + 1);
        atomicAdd(&ws[(b * 40 + slot) * PAD], v);
    } else if (tid >= 64 && tid < 64 + Nc) {
        const int n = tid - 64;
        const float c = cpart[0][n] + cpart[1][n] + cpart[2][n] + cpart[3][n];
        atomicAdd(&ws[(b * 40 + n * 5 + 1) * PAD], c);
    }
}

__global__ __launch_bounds__(64) void niou_final(
    const float* __restrict__ ws, float* __restrict__ out)
{
    const int t = threadIdx.x;   // 0..63 == b*8+n
    const float* w = ws + (size_t)t * 5 * PAD;
    const float sim   = w[0 * PAD];
    const float cnt   = w[1 * PAD];
    const float inter = w[2 * PAD];
    const float gts   = w[3 * PAD];
    const float xo    = w[4 * PAD];
    const float punish = sim / (cnt + EPSc);
    const float iou    = inter / (gts + xo + EPSc);
    float term = 1.0f - iou + punish;
#pragma unroll
    for (int off = 32; off; off >>= 1) term += __shfl_xor(term, off, 64);
    if (t == 0) out[0] = term * (1.0f / 64.0f);
}

extern "C" void kernel_launch(void* const* d_in, const int* in_sizes, int n_in,
                              void* d_out, int out_size, void* d_ws, size_t ws_size,
                              hipStream_t stream) {
    const float* pd_rgbo = (const float*)d_in[0];
    const float* gt_rgbo = (const float*)d_in[1];
    const int*   pd_mask = (const int*)d_in[2];
    const int*   gt_mask = (const int*)d_in[3];
    float* out = (float*)d_out;
    float* ws  = (float*)d_ws;

    hipMemsetAsync(ws, 0, Bc * 40 * PAD * sizeof(float), stream);
    niou_partial<<<Bc * 128, 256, 0, stream>>>(pd_rgbo, gt_rgbo, pd_mask, gt_mask, ws);
    niou_final<<<1, 64, 0, stream>>>(ws, out);
}